// Round 1
// baseline (95.479 us; speedup 1.0000x reference)
//
#include <hip/hip_runtime.h>
#include <math.h>

#define BINS 10
#define BLOCK 256
#define NBLOCKS_MAX 2048

// ---------------------------------------------------------------------------
// Pass 1: one sweep over all elements. Per-thread statically-indexed bin
// accumulators (counts + fp32 bce sums), wave shuffle-reduce, per-block
// partials written (non-atomically) to workspace.
// ---------------------------------------------------------------------------

__device__ __forceinline__ void proc_elem(float xv, float tv,
                                          int cnt[BINS], float sm[BINS]) {
    float ax = fabsf(xv);
    float e  = __expf(-ax);                    // exp(-|x|), in (0,1]
    float dr = 1.0f / (1.0f + e);
    // stable sigmoid: x>=0 -> 1/(1+e) ; x<0 -> e/(1+e)
    float sig = ((xv >= 0.0f) ? 1.0f : e) * dr;
    float g = fabsf(sig - tv);
    int bi = (int)(g * 9.9999f);               // floor, g >= 0
    bi = bi > (BINS - 1) ? (BINS - 1) : bi;
    // stable BCE-with-logits: max(x,0) - x*t + log1p(exp(-|x|))
    float bce = fmaxf(xv, 0.0f) - xv * tv + log1pf(e);
#pragma unroll
    for (int b = 0; b < BINS; ++b) {           // static indexing -> registers
        bool m = (bi == b);
        cnt[b] += m ? 1 : 0;
        sm[b]  += m ? bce : 0.0f;
    }
}

__global__ __launch_bounds__(BLOCK) void ghm_pass1(
        const float4* __restrict__ x4, const float4* __restrict__ t4,
        const float* __restrict__ x, const float* __restrict__ t,
        float* __restrict__ psum, unsigned int* __restrict__ pcnt,
        int nvec, int total) {
    int cnt[BINS];
    float sm[BINS];
#pragma unroll
    for (int b = 0; b < BINS; ++b) { cnt[b] = 0; sm[b] = 0.0f; }

    const int stride = gridDim.x * blockDim.x;
    int gid = blockIdx.x * blockDim.x + threadIdx.x;

    for (int i = gid; i < nvec; i += stride) {
        float4 xv = x4[i];
        float4 tv = t4[i];
        proc_elem(xv.x, tv.x, cnt, sm);
        proc_elem(xv.y, tv.y, cnt, sm);
        proc_elem(xv.z, tv.z, cnt, sm);
        proc_elem(xv.w, tv.w, cnt, sm);
    }
    // scalar tail (not hit for this shape; kept for safety)
    for (int i = nvec * 4 + gid; i < total; i += stride)
        proc_elem(x[i], t[i], cnt, sm);

    // reduce: wave shuffle -> LDS -> per-block partial
    __shared__ float        ws_s[BLOCK / 64][BINS];
    __shared__ unsigned int ws_c[BLOCK / 64][BINS];
    const int lane = threadIdx.x & 63;
    const int wid  = threadIdx.x >> 6;
#pragma unroll
    for (int b = 0; b < BINS; ++b) {
        float s = sm[b];
        int   c = cnt[b];
#pragma unroll
        for (int off = 32; off > 0; off >>= 1) {
            s += __shfl_down(s, off);
            c += __shfl_down(c, off);
        }
        if (lane == 0) { ws_s[wid][b] = s; ws_c[wid][b] = (unsigned int)c; }
    }
    __syncthreads();
    if (threadIdx.x < BINS) {
        int b = threadIdx.x;
        float s = 0.0f;
        unsigned int c = 0;
#pragma unroll
        for (int w = 0; w < BLOCK / 64; ++w) { s += ws_s[w][b]; c += ws_c[w][b]; }
        psum[(size_t)blockIdx.x * BINS + b] = s;
        pcnt[(size_t)blockIdx.x * BINS + b] = c;
    }
}

// ---------------------------------------------------------------------------
// Pass 2: reduce per-block partials (fp64), compute beta per bin exactly as
// the reference (fp32 beta arithmetic), emit the scalar mean.
// ---------------------------------------------------------------------------

__global__ __launch_bounds__(BLOCK) void ghm_pass2(
        const float* __restrict__ psum, const unsigned int* __restrict__ pcnt,
        float* __restrict__ out, int nblocks, float Nf, double inv_total) {
    const int tid  = threadIdx.x;
    const int lane = tid & 63;
    const int wid  = tid >> 6;

    __shared__ double             bin_sum[BINS];
    __shared__ unsigned long long bin_cnt[BINS];
    __shared__ double             w_s[BLOCK / 64];
    __shared__ unsigned long long w_c[BLOCK / 64];

    for (int b = 0; b < BINS; ++b) {
        double s = 0.0;
        unsigned long long c = 0;
        for (int i = tid; i < nblocks; i += BLOCK) {
            s += (double)psum[(size_t)i * BINS + b];
            c += pcnt[(size_t)i * BINS + b];
        }
#pragma unroll
        for (int off = 32; off > 0; off >>= 1) {
            s += __shfl_down(s, off);
            c += __shfl_down(c, off);
        }
        if (lane == 0) { w_s[wid] = s; w_c[wid] = c; }
        __syncthreads();
        if (tid == 0) {
            double ts = 0.0;
            unsigned long long tc = 0;
#pragma unroll
            for (int w = 0; w < BLOCK / 64; ++w) { ts += w_s[w]; tc += w_c[w]; }
            bin_sum[b] = ts;
            bin_cnt[b] = tc;
        }
        __syncthreads();
    }

    if (tid == 0) {
        float nonempty = 0.0f;
#pragma unroll
        for (int b = 0; b < BINS; ++b) nonempty += (bin_cnt[b] > 0) ? 1.0f : 0.0f;
        double acc = 0.0;
#pragma unroll
        for (int b = 0; b < BINS; ++b) {
            float bc   = (float)bin_cnt[b];           // reference keeps fp32
            float gd   = fmaxf(bc * nonempty, 1e-6f);
            float beta = Nf / gd;
            acc += (double)beta * bin_sum[b];
        }
        out[0] = (float)(acc * inv_total);
    }
}

// ---------------------------------------------------------------------------

extern "C" void kernel_launch(void* const* d_in, const int* in_sizes, int n_in,
                              void* d_out, int out_size, void* d_ws, size_t ws_size,
                              hipStream_t stream) {
    const float* x = (const float*)d_in[0];
    const float* t = (const float*)d_in[1];
    const int total = in_sizes[0];          // 1048576 * 16
    const int nvec  = total / 4;
    const int N     = total / 16;           // x.shape[0] (first dim)

    int nblocks = NBLOCKS_MAX;
    size_t per_block = (size_t)BINS * (sizeof(float) + sizeof(unsigned int));
    if ((size_t)nblocks * per_block > ws_size) {
        nblocks = (int)(ws_size / per_block);
        if (nblocks < 1) nblocks = 1;
    }

    float*        psum = (float*)d_ws;
    unsigned int* pcnt = (unsigned int*)((char*)d_ws +
                          (size_t)nblocks * BINS * sizeof(float));

    ghm_pass1<<<nblocks, BLOCK, 0, stream>>>(
        (const float4*)x, (const float4*)t, x, t, psum, pcnt, nvec, total);
    ghm_pass2<<<1, BLOCK, 0, stream>>>(
        psum, pcnt, (float*)d_out, nblocks, (float)N, 1.0 / (double)total);
}

// Round 6
// 40.744 us; speedup vs baseline: 2.3434x; 2.3434x over previous
//
#include <hip/hip_runtime.h>
#include <math.h>

#define BINS 10
#define BLOCK 256
#define NBLOCKS_MAX 2048

// ---------------------------------------------------------------------------
// Pass 1: one sweep. Fast-math transcendentals (v_exp/v_log/v_rcp), packed
// 64-bit bin counter (6 bits/bin, flushed every 56 elems), 10 predicated
// fp32 bce sums (statically indexed -> registers).
// ---------------------------------------------------------------------------

__device__ __forceinline__ void proc_elem(float xv, float tv,
                                          unsigned long long& pc,
                                          float sm[BINS]) {
    const float L2E = 1.44269504088896f;   // log2(e)
    const float LN2 = 0.69314718055995f;   // ln(2)
    float ax  = __builtin_fabsf(xv);
    float e   = __builtin_amdgcn_exp2f(-L2E * ax);     // exp(-|x|)
    float r   = __builtin_amdgcn_rcpf(1.0f + e);       // 1/(1+e)
    float sig = (xv >= 0.0f) ? r : e * r;              // stable sigmoid
    float g   = __builtin_fabsf(sig - tv);
    int bi = (int)(g * 9.9999f);                       // floor, g in [0,1)
    bi = bi > (BINS - 1) ? (BINS - 1) : bi;            // clamp (rcp ulp safety)
    float l2  = __builtin_amdgcn_logf(1.0f + e);       // log2(1+e)
    float bce = __builtin_fmaf(-xv, tv, __builtin_fmaxf(xv, 0.0f));
    bce = __builtin_fmaf(LN2, l2, bce);                // + ln(1+e)
    pc += 1ull << (6 * bi);
#pragma unroll
    for (int b = 0; b < BINS; ++b)
        sm[b] += (bi == b) ? bce : 0.0f;
}

__global__ __launch_bounds__(BLOCK) void ghm_pass1(
        const float4* __restrict__ x4, const float4* __restrict__ t4,
        const float* __restrict__ x, const float* __restrict__ t,
        float* __restrict__ psum, unsigned int* __restrict__ pcnt,
        int nvec, int total) {
    int   cnt[BINS];
    float sm[BINS];
#pragma unroll
    for (int b = 0; b < BINS; ++b) { cnt[b] = 0; sm[b] = 0.0f; }

    const int stride = gridDim.x * blockDim.x;
    const int gid0   = blockIdx.x * blockDim.x + threadIdx.x;

    int i = gid0;
    while (i < nvec) {
        unsigned long long pc = 0ull;
        // 14 float4 iters = 56 elems max per bin < 64 (6-bit field cap)
        for (int it = 0; it < 14 && i < nvec; ++it, i += stride) {
            float4 xv = x4[i];
            float4 tv = t4[i];
            proc_elem(xv.x, tv.x, pc, sm);
            proc_elem(xv.y, tv.y, pc, sm);
            proc_elem(xv.z, tv.z, pc, sm);
            proc_elem(xv.w, tv.w, pc, sm);
        }
#pragma unroll
        for (int b = 0; b < BINS; ++b)
            cnt[b] += (int)((pc >> (6 * b)) & 63ull);
    }
    // scalar tail (not hit for this shape)
    for (int j = nvec * 4 + gid0; j < total; j += stride) {
        unsigned long long pc = 0ull;
        proc_elem(x[j], t[j], pc, sm);
#pragma unroll
        for (int b = 0; b < BINS; ++b)
            cnt[b] += (int)((pc >> (6 * b)) & 63ull);
    }

    // reduce: wave shuffle -> LDS -> per-block partial
    __shared__ float        ws_s[BLOCK / 64][BINS];
    __shared__ unsigned int ws_c[BLOCK / 64][BINS];
    const int lane = threadIdx.x & 63;
    const int wid  = threadIdx.x >> 6;
#pragma unroll
    for (int b = 0; b < BINS; ++b) {
        float s = sm[b];
        int   c = cnt[b];
#pragma unroll
        for (int off = 32; off > 0; off >>= 1) {
            s += __shfl_down(s, off);
            c += __shfl_down(c, off);
        }
        if (lane == 0) { ws_s[wid][b] = s; ws_c[wid][b] = (unsigned int)c; }
    }
    __syncthreads();
    if (threadIdx.x < BINS) {
        int b = threadIdx.x;
        float s = 0.0f;
        unsigned int c = 0;
#pragma unroll
        for (int w = 0; w < BLOCK / 64; ++w) { s += ws_s[w][b]; c += ws_c[w][b]; }
        psum[(size_t)blockIdx.x * BINS + b] = s;
        pcnt[(size_t)blockIdx.x * BINS + b] = c;
    }
}

// ---------------------------------------------------------------------------
// Pass 2: single strided sweep over partials (10 static accumulators per
// thread), one wave+LDS reduce, beta math as in the reference (fp32).
// ---------------------------------------------------------------------------

__global__ __launch_bounds__(BLOCK) void ghm_pass2(
        const float* __restrict__ psum, const unsigned int* __restrict__ pcnt,
        float* __restrict__ out, int nblocks, float Nf, double inv_total) {
    double       s[BINS];
    unsigned int c[BINS];
#pragma unroll
    for (int b = 0; b < BINS; ++b) { s[b] = 0.0; c[b] = 0u; }

    for (int i = threadIdx.x; i < nblocks; i += BLOCK) {
#pragma unroll
        for (int b = 0; b < BINS; ++b) {
            s[b] += (double)psum[(size_t)i * BINS + b];
            c[b] += pcnt[(size_t)i * BINS + b];
        }
    }

    __shared__ double       ls[BLOCK / 64][BINS];
    __shared__ unsigned int lc[BLOCK / 64][BINS];
    const int lane = threadIdx.x & 63;
    const int wid  = threadIdx.x >> 6;
#pragma unroll
    for (int b = 0; b < BINS; ++b) {
        double       sb = s[b];
        unsigned int cb = c[b];
#pragma unroll
        for (int off = 32; off > 0; off >>= 1) {
            sb += __shfl_down(sb, off);
            cb += __shfl_down(cb, off);
        }
        if (lane == 0) { ls[wid][b] = sb; lc[wid][b] = cb; }
    }
    __syncthreads();

    if (threadIdx.x == 0) {
        double             bin_sum[BINS];
        unsigned long long bin_cnt[BINS];
#pragma unroll
        for (int b = 0; b < BINS; ++b) {
            double ts = 0.0;
            unsigned long long tc = 0;
#pragma unroll
            for (int w = 0; w < BLOCK / 64; ++w) { ts += ls[w][b]; tc += lc[w][b]; }
            bin_sum[b] = ts;
            bin_cnt[b] = tc;
        }
        float nonempty = 0.0f;
#pragma unroll
        for (int b = 0; b < BINS; ++b) nonempty += (bin_cnt[b] > 0) ? 1.0f : 0.0f;
        double acc = 0.0;
#pragma unroll
        for (int b = 0; b < BINS; ++b) {
            float bc   = (float)bin_cnt[b];            // reference keeps fp32
            float gd   = fmaxf(bc * nonempty, 1e-6f);
            float beta = Nf / gd;
            acc += (double)beta * bin_sum[b];
        }
        out[0] = (float)(acc * inv_total);
    }
}

// ---------------------------------------------------------------------------

extern "C" void kernel_launch(void* const* d_in, const int* in_sizes, int n_in,
                              void* d_out, int out_size, void* d_ws, size_t ws_size,
                              hipStream_t stream) {
    const float* x = (const float*)d_in[0];
    const float* t = (const float*)d_in[1];
    const int total = in_sizes[0];          // 1048576 * 16
    const int nvec  = total / 4;
    const int N     = total / 16;           // x.shape[0] (first dim)

    int nblocks = NBLOCKS_MAX;
    size_t per_block = (size_t)BINS * (sizeof(float) + sizeof(unsigned int));
    if ((size_t)nblocks * per_block > ws_size) {
        nblocks = (int)(ws_size / per_block);
        if (nblocks < 1) nblocks = 1;
    }

    float*        psum = (float*)d_ws;
    unsigned int* pcnt = (unsigned int*)((char*)d_ws +
                          (size_t)nblocks * BINS * sizeof(float));

    ghm_pass1<<<nblocks, BLOCK, 0, stream>>>(
        (const float4*)x, (const float4*)t, x, t, psum, pcnt, nvec, total);
    ghm_pass2<<<1, BLOCK, 0, stream>>>(
        psum, pcnt, (float*)d_out, nblocks, (float)N, 1.0 / (double)total);
}